// Round 15
// baseline (49.683 us; speedup 1.0000x reference)
//
#include <hip/hip_runtime.h>
#include <math.h>

#define NCLS 91
#define FDIM 256
#define NB   256                   // mainpass blocks (= partials), 1 per CU
#define BINSZ  (NCLS * FDIM)       // 23296
#define BINSZP (92 * FDIM)         // 23552, padded stride (4-class reduce tiles)
#define NRED 8                     // stage-1 reduction: 8 groups of 32 partials

typedef float f32x4 __attribute__((ext_vector_type(4)));
typedef short short8 __attribute__((ext_vector_type(8)));

__device__ __forceinline__ float wave_sum64(float ss) {
    #pragma unroll
    for (int m = 1; m < 64; m <<= 1) ss += __shfl_xor(ss, m, 64);
    return ss;
}
__device__ __forceinline__ int wave_sum64_i(int v) {
    #pragma unroll
    for (int m = 1; m < 64; m <<= 1) v += __shfl_xor(v, m, 64);
    return v;
}

template <int CTRL>
__device__ __forceinline__ float dpp_addstep(float v) {
    return v + __int_as_float(__builtin_amdgcn_mov_dpp(
        __float_as_int(v), CTRL, 0xf, 0xf, true));
}
__device__ __forceinline__ float group16_sum(float v) {
    v = dpp_addstep<0xB1>(v);
    v = dpp_addstep<0x1B>(v);
    v = dpp_addstep<0x141>(v);
    v = dpp_addstep<0x140>(v);
    return v;
}

__device__ __forceinline__ unsigned short f2bf(float x) {   // RNE f32->bf16
    unsigned u = __float_as_uint(x);
    return (unsigned short)((u + 0x7FFFu + ((u >> 16) & 1u)) >> 16);
}
__device__ __forceinline__ float bf2f(unsigned short h) {
    return __uint_as_float((unsigned)h << 16);
}

// ---------------- K1: streaming normalize + one-hot MFMA segment-sum ----------------
// R14: loads issued at the TOP of each inter-barrier window (ping-pong register
// sets RS0/RS1, 2-chunk unrolled loop) so the MFMA+stage phase covers HBM latency
// and the compiler's vmcnt(0)-before-s_barrier drain finds loads complete.
// (R13 issued prefetch right before the barrier -> ~900cy stall per chunk.)
#define MPT 1024
#define CHUNK 64
#define ROWSTRIDE 260              // u16 units; 520B, qword-stride 65

extern "C" __global__ void __launch_bounds__(MPT)
mfma_main(const float* __restrict__ feats, const int* __restrict__ labels,
          unsigned short* __restrict__ slices, unsigned int* __restrict__ cnts_ws,
          int nrows, int rpb)
{
    __shared__ __align__(16) unsigned short sdat[2][CHUNK * ROWSTRIDE];
    __shared__ __align__(8)  unsigned char  slbl[2][CHUNK];
    __shared__ unsigned int scnt[96];

    const int tid  = threadIdx.x;
    const int lane = tid & 63;
    const int w    = tid >> 6;        // wave 0..15 -> d-tile
    const int l16  = lane & 15;
    const int g    = lane >> 4;       // lane group 0..3
    const int d0   = w * 16;
    const int r_loc = w * 4 + g;      // the row this lane stages

    if (tid < 96) scnt[tid] = 0u;

    const int row0 = blockIdx.x * rpb;
    const int nch  = rpb / CHUNK;     // even (rpb multiple of 128)

    f32x4 acc[6];
    #pragma unroll
    for (int ct = 0; ct < 6; ++ct) acc[ct] = (f32x4){0.f, 0.f, 0.f, 0.f};

    float4 A0, A1, A2, A3; int labA;  // register set RS0
    float4 B0, B1, B2, B3; int labB;  // register set RS1

    auto loadA = [&](int ch) {
        const int r = row0 + ch * CHUNK + r_loc;
        if (r < nrows) {
            const float4* bp = (const float4*)(feats + (size_t)r * FDIM + l16 * 16);
            A0 = bp[0]; A1 = bp[1]; A2 = bp[2]; A3 = bp[3];
            labA = labels[r];
        } else {
            A0 = A1 = A2 = A3 = make_float4(0.f, 0.f, 0.f, 0.f);
            labA = 255;
        }
    };
    auto loadB = [&](int ch) {
        const int r = row0 + ch * CHUNK + r_loc;
        if (r < nrows) {
            const float4* bp = (const float4*)(feats + (size_t)r * FDIM + l16 * 16);
            B0 = bp[0]; B1 = bp[1]; B2 = bp[2]; B3 = bp[3];
            labB = labels[r];
        } else {
            B0 = B1 = B2 = B3 = make_float4(0.f, 0.f, 0.f, 0.f);
            labB = 255;
        }
    };

    auto stage = [&](int buf, const float4& p0, const float4& p1,
                     const float4& p2, const float4& p3, int plab) {
        float ss = 0.f;
        ss = fmaf(p0.x, p0.x, ss); ss = fmaf(p0.y, p0.y, ss);
        ss = fmaf(p0.z, p0.z, ss); ss = fmaf(p0.w, p0.w, ss);
        ss = fmaf(p1.x, p1.x, ss); ss = fmaf(p1.y, p1.y, ss);
        ss = fmaf(p1.z, p1.z, ss); ss = fmaf(p1.w, p1.w, ss);
        ss = fmaf(p2.x, p2.x, ss); ss = fmaf(p2.y, p2.y, ss);
        ss = fmaf(p2.z, p2.z, ss); ss = fmaf(p2.w, p2.w, ss);
        ss = fmaf(p3.x, p3.x, ss); ss = fmaf(p3.y, p3.y, ss);
        ss = fmaf(p3.z, p3.z, ss); ss = fmaf(p3.w, p3.w, ss);
        ss = group16_sum(ss);
        const float inv = 1.0f / fmaxf(sqrtf(ss), 1e-12f);
        unsigned long long* q =
            (unsigned long long*)&sdat[buf][0] + (size_t)r_loc * 65 + l16 * 4;
        const float e[16] = {p0.x, p0.y, p0.z, p0.w, p1.x, p1.y, p1.z, p1.w,
                             p2.x, p2.y, p2.z, p2.w, p3.x, p3.y, p3.z, p3.w};
        #pragma unroll
        for (int t = 0; t < 4; ++t) {
            unsigned long long v =
                (unsigned long long)f2bf(e[4 * t + 0] * inv)
              | ((unsigned long long)f2bf(e[4 * t + 1] * inv) << 16)
              | ((unsigned long long)f2bf(e[4 * t + 2] * inv) << 32)
              | ((unsigned long long)f2bf(e[4 * t + 3] * inv) << 48);
            q[t] = v;
        }
        if (l16 == 0) {
            slbl[buf][r_loc] = (unsigned char)plab;
            if (plab < 96) atomicAdd(&scnt[plab], 1u);
        }
    };

    auto mfma_phase = [&](int buf) {
        #pragma unroll
        for (int s = 0; s < 2; ++s) {
            const int kbase = s * 32 + g * 8;
            const unsigned long long lb =
                *(const unsigned long long*)&slbl[buf][kbase];
            int la[8];
            #pragma unroll
            for (int j = 0; j < 8; ++j) la[j] = (int)((lb >> (8 * j)) & 0xFFu);

            short8 b;
            #pragma unroll
            for (int j = 0; j < 8; ++j)
                b[j] = (short)sdat[buf][(size_t)(kbase + j) * ROWSTRIDE + d0 + l16];

            #pragma unroll
            for (int ct = 0; ct < 6; ++ct) {
                const int c = ct * 16 + l16;     // A row m = lane&15
                short8 a;
                #pragma unroll
                for (int j = 0; j < 8; ++j)
                    a[j] = (la[j] == c) ? (short)0x3F80 : (short)0;
                acc[ct] = __builtin_amdgcn_mfma_f32_16x16x32_bf16(a, b, acc[ct], 0, 0, 0);
            }
        }
    };

    // ---- prologue ----
    loadA(0);
    __syncthreads();                  // scnt init visible before first stage atomic
    stage(0, A0, A1, A2, A3, labA);   // chunk 0 -> buf0
    loadA(1);                         // RS0 <- chunk 1 (in flight)
    __syncthreads();                  // drains chunk-1 loads (once, prologue)

    // ---- main loop: 2 chunks per iteration, loads issued at window top ----
    for (int p = 0; p < nch; p += 2) {
        // window A: MFMA chunk p (buf0), stage chunk p+1 (buf1) from RS0
        if (p + 2 < nch) loadB(p + 2);          // issue early; covered by MFMA
        mfma_phase(0);
        stage(1, A0, A1, A2, A3, labA);          // chunk p+1 (p+1 < nch always)
        __syncthreads();

        // window B: MFMA chunk p+1 (buf1), stage chunk p+2 (buf0) from RS1
        if (p + 3 < nch) loadA(p + 3);
        mfma_phase(1);
        if (p + 2 < nch) stage(0, B0, B1, B2, B3, labB);
        __syncthreads();
    }

    // ---- epilogue: acc -> bf16 via LDS transpose (sdat[0] reused), stream out ----
    unsigned short* es = &sdat[0][0];
    #pragma unroll
    for (int ct = 0; ct < 6; ++ct) {
        #pragma unroll
        for (int reg = 0; reg < 4; ++reg) {
            const int c = ct * 16 + g * 4 + reg;   // C row = (lane>>4)*4+reg [m89]
            if (c < NCLS)
                es[c * FDIM + d0 + l16] = f2bf(acc[ct][reg]);
        }
    }
    __syncthreads();
    {
        const unsigned long long* src = (const unsigned long long*)es;
        unsigned long long* dst =
            (unsigned long long*)(slices + (size_t)blockIdx.x * BINSZP);
        for (int i = tid; i < BINSZ / 4; i += MPT) dst[i] = src[i];
    }
    if (tid < 96) cnts_ws[(size_t)blockIdx.x * 96 + tid] = scnt[tid];
}

// ---------------- K2: stage-1 slice reduction (4-class tiles, ulong reads) ----------------
// grid (23, NRED): block (t4, h) covers classes [4*t4, 4*t4+4), partials
// [h*32, h*32+32). Thread t reads ulong (4 u16) -> 512B coalesced per wave row.
extern "C" __global__ void __launch_bounds__(FDIM)
reduce_k(const unsigned short* __restrict__ slices, float* __restrict__ part2)
{
    const int t4 = blockIdx.x;
    const int h  = blockIdx.y;
    const int t  = threadIdx.x;
    const int off = t4 * 1024 + t * 4;          // u16 offset within a partial
    const int p0 = h * (NB / NRED);

    float s0 = 0.f, s1 = 0.f, s2 = 0.f, s3 = 0.f;
    #pragma unroll 1
    for (int p = 0; p < NB / NRED; p += 4) {
        #pragma unroll
        for (int u = 0; u < 4; ++u) {
            const unsigned long long v = *(const unsigned long long*)
                (slices + (size_t)(p0 + p + u) * BINSZP + off);
            s0 += bf2f((unsigned short)(v));
            s1 += bf2f((unsigned short)(v >> 16));
            s2 += bf2f((unsigned short)(v >> 32));
            s3 += bf2f((unsigned short)(v >> 48));
        }
    }
    float4* dst = (float4*)(part2 + (size_t)h * BINSZP + off);
    *dst = make_float4(s0, s1, s2, s3);
}

// ---------------- bool / scalar dtype detection ----------------
__device__ int detect_bool_enc(const void* p) {
    const unsigned int* u = (const unsigned int*)p;
    bool i32ok = true, f32ok = true;
    for (int i = 0; i < 22; ++i) {
        unsigned int w = u[i];
        if (w > 1u) i32ok = false;
        if (w != 0u && w != 0x3F800000u) f32ok = false;
    }
    return i32ok ? 1 : (f32ok ? 2 : 0);
}
__device__ bool read_bool(const void* p, int enc, int i) {
    if (enc == 1) return ((const unsigned int*)p)[i] != 0u;
    if (enc == 2) return ((const float*)p)[i] != 0.0f;
    return ((const unsigned char*)p)[i] != 0;
}
__device__ int read_step(const void* p) {
    unsigned int w = ((const unsigned int*)p)[0];
    int iv = (int)w;
    if (iv >= 0 && iv < 16777216) return iv;
    return (int)__uint_as_float(w);
}

// ---------------- K3: final per-class math ----------------
extern "C" __global__ void __launch_bounds__(FDIM)
final_k(const float* __restrict__ part2, const unsigned int* __restrict__ cnts_ws,
        const float* __restrict__ protos, const void* __restrict__ p_init,
        const float* __restrict__ p_var, const float* __restrict__ shadow,
        const void* __restrict__ s_init, const int* __restrict__ p_count,
        const void* __restrict__ p_step, float* __restrict__ out)
{
    const int c = blockIdx.x;
    const int d = threadIdx.x;

    __shared__ int enc_pi, enc_si;
    __shared__ float red[FDIM / 64];
    __shared__ int credi[FDIM / 64];
    __shared__ float s_upd;
    __shared__ unsigned int s_cnt;
    if (d == 0) { enc_pi = detect_bool_enc(p_init); enc_si = detect_bool_enc(s_init); }

    int cpart = 0;
    for (int p = d; p < NB; p += FDIM)
        cpart += (int)cnts_ws[(size_t)p * 96 + c];
    int cw = wave_sum64_i(cpart);
    if ((d & 63) == 0) credi[d >> 6] = cw;
    __syncthreads();
    if (d == 0) s_cnt = (unsigned int)(credi[0] + credi[1] + credi[2] + credi[3]);

    const int slot = c * FDIM + d;
    float sum = 0.f;
    #pragma unroll
    for (int h = 0; h < NRED; ++h) sum += part2[(size_t)h * BINSZP + slot];
    __syncthreads();

    const unsigned int cnt = s_cnt;
    const bool present = cnt > 0u;
    const float cls = sum / fmaxf((float)cnt, 1.0f);
    const float oldp = protos[c * FDIM + d];

    const float diff = cls - oldp;
    float ds = wave_sum64(diff * diff);
    if ((d & 63) == 0) red[d >> 6] = ds;
    __syncthreads();
    if (d == 0) s_upd = sqrtf(red[0] + red[1] + red[2] + red[3] + 1e-24f);
    __syncthreads();
    const float upd_mag = s_upd;

    const bool  init  = read_bool(p_init, enc_pi, c);
    const bool  sinit = read_bool(s_init, enc_si, c);
    const float var   = p_var[c];
    const int   step  = read_step(p_step);

    const float progress = fminf(1.0f, (float)step * (1.0f / 2000.0f));
    const float mom = init ? (0.99f + 0.009f * expf(-var) * progress) : 0.99f;

    const float ema   = mom * oldp + (1.0f - mom) * cls;
    const float newp  = present ? (init ? ema : cls) : oldp;

    const float sh     = shadow[c * FDIM + d];
    const float sh_ema = 0.9999f * sh + 0.0001f * newp;
    const float newsh  = present ? (sinit ? sh_ema : newp) : sh;

    const int O1 = NCLS * FDIM;
    const int O2 = O1 + NCLS;
    const int O3 = O2 + NCLS * FDIM;
    const int O4 = O3 + NCLS;
    const int O5 = O4 + NCLS;

    out[c * FDIM + d]       = newp;
    out[O2 + c * FDIM + d]  = newsh;
    if (d == 0) {
        const float newvar = (present && init) ? (0.99f * var + 0.01f * upd_mag) : var;
        out[O1 + c] = newvar;
        out[O3 + c] = (init || present)  ? 1.0f : 0.0f;
        out[O4 + c] = (sinit || present) ? 1.0f : 0.0f;
        out[O5 + c] = (float)(p_count[c] + (present ? 1 : 0));
    }
}

extern "C" void kernel_launch(void* const* d_in, const int* in_sizes, int n_in,
                              void* d_out, int out_size, void* d_ws, size_t ws_size,
                              hipStream_t stream) {
    const float* feats  = (const float*)d_in[0];
    const int*   labels = (const int*)d_in[1];
    const float* protos = (const float*)d_in[2];
    const void*  p_init = d_in[3];
    const float* p_var  = (const float*)d_in[4];
    const float* shadow = (const float*)d_in[5];
    const void*  s_init = d_in[6];
    const int*   p_cnt  = (const int*)d_in[7];
    const void*  p_step = d_in[8];
    const int nrows = in_sizes[1];

    // rows per block: multiple of 2*CHUNK (even chunk count for the 2-unrolled loop)
    int rpb = (nrows + NB - 1) / NB;
    rpb = ((rpb + 2 * CHUNK - 1) / (2 * CHUNK)) * (2 * CHUNK);

    unsigned short* slices  = (unsigned short*)d_ws;                 // [NB][BINSZP] bf16
    unsigned int*   cnts_ws = (unsigned int*)((char*)d_ws + (size_t)BINSZP * NB * 2);
    float*          part2   = (float*)((char*)d_ws + (size_t)BINSZP * NB * 2
                                       + (size_t)NB * 96 * 4);       // [NRED][BINSZP]

    mfma_main<<<NB, MPT, 0, stream>>>(feats, labels, slices, cnts_ws, nrows, rpb);
    reduce_k<<<dim3(23, NRED), FDIM, 0, stream>>>(slices, part2);
    final_k<<<NCLS, FDIM, 0, stream>>>(part2, cnts_ws, protos, p_init, p_var,
                                       shadow, s_init, p_cnt, p_step, (float*)d_out);
}